// Round 10
// baseline (208.528 us; speedup 1.0000x reference)
//
#include <hip/hip_runtime.h>
#include <hip/hip_bf16.h>
#include <cstddef>

#define B_SZ 2
#define SEQ  2048
#define DM   1024
#define NH   16
#define HD   64
#define LAT  256
#define MTOT (B_SZ*SEQ)   // 4096
#define NQKV 1536
#define QSCALE 0.18033688011112042f  // 0.125 * log2(e)

typedef short bf16x8 __attribute__((ext_vector_type(8)));
typedef float floatx4 __attribute__((ext_vector_type(4)));
typedef float floatx16 __attribute__((ext_vector_type(16)));
typedef unsigned short u16;
typedef unsigned uintx2 __attribute__((ext_vector_type(2)));

#if __has_builtin(__builtin_amdgcn_exp2f)
#define EXP2(x) __builtin_amdgcn_exp2f(x)
#else
#define EXP2(x) exp2f(x)
#endif

__device__ __forceinline__ u16 f2bf(float f) {
  union { float f; unsigned u; } a; a.f = f;
  unsigned r = a.u + 0x7FFFu + ((a.u >> 16) & 1u);  // RNE
  return (u16)(r >> 16);
}

__device__ __forceinline__ floatx4 mfma16(bf16x8 a, bf16x8 b, floatx4 c) {
  return __builtin_amdgcn_mfma_f32_16x16x32_bf16(a, b, c, 0, 0, 0);
}

__device__ __forceinline__ floatx16 mfma32(bf16x8 a, bf16x8 b, floatx16 c) {
  return __builtin_amdgcn_mfma_f32_32x32x16_bf16(a, b, c, 0, 0, 0);
}

// async global->LDS, 16B per lane; lds dest = wave-uniform base + lane*16
__device__ __forceinline__ void load16(const u16* g, u16* l) {
  __builtin_amdgcn_global_load_lds((const __attribute__((address_space(1))) unsigned*)g,
                                   (__attribute__((address_space(3))) unsigned*)l, 16, 0, 0);
}

// pack 8 probs to bf16 pairs + lane-half exchange -> PV B-operand (m74/m101 map).
// permlane32_swap (VALU) replaces ds_bpermute (LDS pipe) [T12]: R7->R8 55.3->49.3us.
__device__ __forceinline__ bf16x8 packex(float p0, float p1, float p2, float p3,
                                         float p4, float p5, float p6, float p7, int hi) {
  unsigned w0 = __builtin_amdgcn_perm(__float_as_uint(p1) + 0x8000u,
                                      __float_as_uint(p0) + 0x8000u, 0x07060302u);
  unsigned w1 = __builtin_amdgcn_perm(__float_as_uint(p3) + 0x8000u,
                                      __float_as_uint(p2) + 0x8000u, 0x07060302u);
  unsigned w2 = __builtin_amdgcn_perm(__float_as_uint(p5) + 0x8000u,
                                      __float_as_uint(p4) + 0x8000u, 0x07060302u);
  unsigned w3 = __builtin_amdgcn_perm(__float_as_uint(p7) + 0x8000u,
                                      __float_as_uint(p6) + 0x8000u, 0x07060302u);
  union { unsigned u[4]; bf16x8 v; } bb;
#if __has_builtin(__builtin_amdgcn_permlane32_swap)
  uintx2 r02 = __builtin_amdgcn_permlane32_swap(w0, w2, false, false);
  uintx2 r13 = __builtin_amdgcn_permlane32_swap(w1, w3, false, false);
  bb.u[0] = r02.x; bb.u[1] = r13.x; bb.u[2] = r02.y; bb.u[3] = r13.y;
#else
  unsigned s0 = (unsigned)__shfl_xor((int)w0, 32);
  unsigned s1 = (unsigned)__shfl_xor((int)w1, 32);
  unsigned s2 = (unsigned)__shfl_xor((int)w2, 32);
  unsigned s3 = (unsigned)__shfl_xor((int)w3, 32);
  bb.u[0] = hi ? s2 : w0;
  bb.u[1] = hi ? s3 : w1;
  bb.u[2] = hi ? w2 : s0;
  bb.u[3] = hi ? w3 : s1;
#endif
  return bb.v;
}

// ---------------- mega prep: cast x | 6 weight transposes | bias concat ----------------
__device__ void transpose_tile(const float* __restrict__ W, u16* __restrict__ WT,
                               int K, int N, int k0, int n0, u16 (*t)[65]) {
  const int r = threadIdx.x >> 4;          // 0..15
  const int c4 = (threadIdx.x & 15) * 4;   // 0..60
#pragma unroll
  for (int s = 0; s < 4; s++) {
    int row = s * 16 + r;
    float4 v = *(const float4*)&W[(size_t)(k0 + row) * N + n0 + c4];
    t[row][c4 + 0] = f2bf(v.x); t[row][c4 + 1] = f2bf(v.y);
    t[row][c4 + 2] = f2bf(v.z); t[row][c4 + 3] = f2bf(v.w);
  }
  __syncthreads();
  const int r2 = threadIdx.x >> 2;          // 0..63 (out row = n)
  const int c8 = (threadIdx.x & 3) * 16;    // 0,16,32,48 (out col = k)
  __align__(16) u16 tmp[16];
#pragma unroll
  for (int i = 0; i < 16; i++) tmp[i] = t[c8 + i][r2];
  u16* dst = WT + (size_t)(n0 + r2) * K + k0 + c8;
  *(bf16x8*)dst       = *(const bf16x8*)&tmp[0];
  *(bf16x8*)(dst + 8) = *(const bf16x8*)&tmp[8];
}

__global__ __launch_bounds__(256)
void prep_k(const float* __restrict__ x, u16* __restrict__ xb,
            const float* __restrict__ Wq, const float* __restrict__ Wkd,
            const float* __restrict__ Wvd, const float* __restrict__ Wku,
            const float* __restrict__ Wvu, const float* __restrict__ Wo,
            u16* __restrict__ WstkT, u16* __restrict__ WkuT,
            u16* __restrict__ WvuT, u16* __restrict__ WoT,
            const float* __restrict__ bq, const float* __restrict__ bkd,
            const float* __restrict__ bvd, float* __restrict__ bqkv) {
  __shared__ u16 t[64][65];
  const int blk = blockIdx.x;
  if (blk < 4096) {                 // cast x -> bf16, 1 float4/thread
    int i = blk * 256 + threadIdx.x;
    float4 v = ((const float4*)x)[i];
    ushort4 o; o.x = f2bf(v.x); o.y = f2bf(v.y); o.z = f2bf(v.z); o.w = f2bf(v.w);
    ((ushort4*)xb)[i] = o;
  } else if (blk < 4352) {          // Wq^T -> WstkT[0:1024]
    int tt = blk - 4096;
    transpose_tile(Wq, WstkT, DM, DM, (tt >> 4) * 64, (tt & 15) * 64, t);
  } else if (blk < 4416) {          // Wkd^T -> WstkT[1024:1280]
    int tt = blk - 4352;
    transpose_tile(Wkd, WstkT + (size_t)DM * DM, DM, LAT, (tt >> 2) * 64, (tt & 3) * 64, t);
  } else if (blk < 4480) {          // Wvd^T -> WstkT[1280:1536]
    int tt = blk - 4416;
    transpose_tile(Wvd, WstkT + (size_t)1280 * DM, DM, LAT, (tt >> 2) * 64, (tt & 3) * 64, t);
  } else if (blk < 4544) {          // Wku^T
    int tt = blk - 4480;
    transpose_tile(Wku, WkuT, LAT, DM, (tt >> 4) * 64, (tt & 15) * 64, t);
  } else if (blk < 4608) {          // Wvu^T
    int tt = blk - 4544;
    transpose_tile(Wvu, WvuT, LAT, DM, (tt >> 4) * 64, (tt & 15) * 64, t);
  } else if (blk < 4864) {          // Wo^T
    int tt = blk - 4608;
    transpose_tile(Wo, WoT, DM, DM, (tt >> 4) * 64, (tt & 15) * 64, t);
  } else {                          // bias concat (6 blocks)
    int i = (blk - 4864) * 256 + threadIdx.x;
    float v = (i < 1024) ? bq[i] : (i < 1280) ? bkd[i - 1024] : bvd[i - 1280];
    bqkv[i] = v;
  }
}

// ---------------- GEMM: C = A * BT^T + bias ----------------
// R10: TN template param. 128x128 tiles for the K=1024 GEMMs (QKV, Wo): each
// wave owns a 64x64 quadrant, acc 4x4 -> 32 MFMAs per 16 ds_reads per k-step
// (2:1, m97/m93-proven config; was 16 MFMAs per 12 reads = 1.33:1 at 128x64).
// Halves staged bytes per FLOP. GEMM2 (K=256, 4 k-steps) keeps 128x64 — too
// few k-steps to amortize a bigger tile. K-loop: R9's 1-barrier double-buffer
// (2-phase). A/B purpose: if the GEMMs are the ~145us non-attn cost, total
// drops to ~170; if total stays ~200, the cost is overhead/prep -> pivot.
// LDS: TN=128 -> 64KB (2 blocks/CU); TN=64 -> 48KB (3 blocks/CU).
template<int TM, int TN, int OUT_BF16, int VT1>
__global__ __launch_bounds__(256)
void gemm_bt(const u16* __restrict__ A0, const u16* __restrict__ A1,
             const u16* __restrict__ BT0, const u16* __restrict__ BT1,
             const float* __restrict__ bias0, const float* __restrict__ bias1,
             void* __restrict__ C0, void* __restrict__ C1,
             int M, int N, int Kd, int lda, float qscale, int qcols) {
  constexpr int FI = TM / 32;       // A-frags per wave along M (wave tile TM/2)
  constexpr int FJ = TN / 32;       // B-frags per wave along N (wave tile TN/2)
  __shared__ u16 As[2][TM * 64];
  __shared__ u16 Bs[2][TN * 64];
  const u16* A  = blockIdx.z ? A1 : A0;
  const u16* BT = blockIdx.z ? BT1 : BT0;
  const float* bias = blockIdx.z ? bias1 : bias0;
  void* C = blockIdx.z ? C1 : C0;

  const int tid = threadIdx.x;
  const int m0 = blockIdx.y * TM, n0 = blockIdx.x * TN;
  const int wave = tid >> 6, lane = tid & 63;
  const int l15 = lane & 15, quad = lane >> 4;
  const int wm = (wave >> 1) * (TM / 2), wn = (wave & 1) * (TN / 2);

  floatx4 acc[FI][FJ];
#pragma unroll
  for (int i = 0; i < FI; i++)
#pragma unroll
    for (int j = 0; j < FJ; j++) acc[i][j] = (floatx4){0.f, 0.f, 0.f, 0.f};

  const int tr = tid >> 3;          // 0..31
  const int tc8 = (tid & 7) * 8;
  const u16* Ag = A  + (size_t)(m0 + tr) * lda + tc8;
  const u16* Bg = BT + (size_t)(n0 + tr) * Kd + tc8;

  // stage 64-K slab k0 into buffer buf
  auto stage = [&](int k0, int buf) {
#pragma unroll
    for (int s = 0; s < TM / 32; s++)
      load16(Ag + (size_t)(s * 32) * lda + k0, &As[buf][(size_t)tid * 8 + s * 2048]);
#pragma unroll
    for (int s = 0; s < TN / 32; s++)
      load16(Bg + (size_t)(s * 32) * Kd  + k0, &Bs[buf][(size_t)tid * 8 + s * 2048]);
  };

  stage(0, 0);
  __syncthreads();                  // vmcnt(0) drain: buf0 ready

  int buf = 0;
  for (int k0 = 0; k0 < Kd; k0 += 64, buf ^= 1) {
    if (k0 + 64 < Kd) stage(k0 + 64, buf ^ 1);   // async, overlaps compute below
#pragma unroll
    for (int kk = 0; kk < 2; kk++) {
      bf16x8 af[FI], bfr[FJ];
#pragma unroll
      for (int i = 0; i < FI; i++)
        af[i]  = *(const bf16x8*)&As[buf][(wm + i * 16 + l15) * 64 + kk * 32 + quad * 8];
#pragma unroll
      for (int j = 0; j < FJ; j++)
        bfr[j] = *(const bf16x8*)&Bs[buf][(wn + j * 16 + l15) * 64 + kk * 32 + quad * 8];
#pragma unroll
      for (int i = 0; i < FI; i++)
#pragma unroll
        for (int j = 0; j < FJ; j++)
          acc[i][j] = mfma16(af[i], bfr[j], acc[i][j]);
    }
    __syncthreads();                // drains k+1 loads + frees buf for overwrite
  }

  if (VT1 && blockIdx.z == 1) {
    // write V in transposed per-head layout: VT[(b*16+h)*64+d][s]
#pragma unroll
    for (int i = 0; i < FI; i++) {
      int row = m0 + wm + i * 16 + quad * 4;    // b*2048 + s (s ≡ 0 mod 4)
      int bb = row >> 11, sb = row & 2047;
#pragma unroll
      for (int j = 0; j < FJ; j++) {
        int col = n0 + wn + j * 16 + l15;       // h*64 + d
        float bv = bias[col];
        union { u16 u[4]; uint2 w2; } tv;
#pragma unroll
        for (int r = 0; r < 4; r++) tv.u[r] = f2bf(acc[i][j][r] + bv);
        *(uint2*)((u16*)C + ((size_t)(bb * 16 + (col >> 6)) * 64 + (col & 63)) * SEQ + sb) = tv.w2;
      }
    }
  } else {
#pragma unroll
    for (int i = 0; i < FI; i++) {
      int row = m0 + wm + i * 16 + quad * 4;
#pragma unroll
      for (int j = 0; j < FJ; j++) {
        int col = n0 + wn + j * 16 + l15;
        float bv = bias[col];
        float sc = (col < qcols) ? qscale : 1.f;
#pragma unroll
        for (int r = 0; r < 4; r++) {
          float v = (acc[i][j][r] + bv) * sc;
          if (OUT_BF16) ((u16*)C)[(size_t)(row + r) * N + col] = f2bf(v);
          else          ((float*)C)[(size_t)(row + r) * N + col] = v;
        }
      }
    }
  }
}

// ---------------- fused attention (2 q-tiles/wave, permlane half-exchange) ----------------
// FROZEN (2nd round) — isolating GEMM changes. State: 49-55us (run-to-run band
// ±5us, rule #19 co-compile perturbation), MfmaUtil 24-28% (= MFMA-cycle floor),
// VALU ~36%, conflicts 2.1M, VGPR 128, no spill.
__global__ __launch_bounds__(256, 2)
void attn_fused(const u16* __restrict__ Q, const u16* __restrict__ K,
                const u16* __restrict__ VT, u16* __restrict__ CTX) {
  __shared__ __align__(16) u16 KVt[2][2][2][64][64];  // [kw][buf][K/V][row][64] = 64 KiB
  const int lin = blockIdx.y * gridDim.x + blockIdx.x;
  const int idx = lin >> 3;
  const int bh = (lin & 7) * 4 + (idx >> 4);   // XCD (lin%8) owns bh group of 4
  const int q0 = (idx & 15) * 128;
  const int b = bh >> 4, h = bh & 15;
  const int wave = threadIdx.x >> 6, lane = threadIdx.x & 63;
  const int qw = wave & 1;                     // q sub-tile pair 0..1 (64 rows each)
  const int kw = wave >> 1;                    // key half 0/1
  const int l31 = lane & 31;
  const int hi = lane >> 5;                    // lane half: 0/1
  const int lr = lane >> 3;                    // staging row-within-8 (0..7)
  const int cx = (lane & 7) ^ lr;              // pre-swizzled source chunk

  // Q as B-operand for 2 q-tiles: qf{0,1}[dc] = Q[q0+qw*64+qt*32+l31][h*64+dc*16+hi*8+j]
  bf16x8 qf0[4], qf1[4];
  {
    const u16* Qp = Q + (size_t)(b * SEQ + q0 + qw * 64 + l31) * NQKV + h * HD + hi * 8;
#pragma unroll
    for (int dc = 0; dc < 4; dc++) {
      qf0[dc] = *(const bf16x8*)(Qp + dc * 16);
      qf1[dc] = *(const bf16x8*)(Qp + (size_t)32 * NQKV + dc * 16);
    }
  }

  // staging sources (pre-swizzled): wave stages rows [qw*32, qw*32+32) of its
  // kw-half tile, via 4 instr K + 4 instr V (8 rows each).
  const u16* Kbase = K + (size_t)(b * SEQ + kw * 1024 + qw * 32 + lr) * DM + h * HD + cx * 8;
  const u16* Vbase = VT + ((size_t)bh * HD + qw * 32 + lr) * SEQ + kw * 1024 + cx * 8;

  floatx16 o00, o01, o10, o11;   // o[qt][dh]: ctx^T 32x32 tiles (row d, col q=l31)
  const floatx16 zf16 = {0.f,0.f,0.f,0.f,0.f,0.f,0.f,0.f,0.f,0.f,0.f,0.f,0.f,0.f,0.f,0.f};
  o00 = zf16; o01 = zf16; o10 = zf16; o11 = zf16;
  float ls0 = 0.f, ls1 = 0.f;

  // prologue: stage tile 0 into buf 0 of this kw half
#pragma unroll
  for (int s = 0; s < 4; s++) {
    load16(Kbase + (size_t)(s * 8) * DM, &KVt[kw][0][0][qw * 32 + s * 8][0]);
    load16(Vbase + (size_t)(s * 8) * SEQ, &KVt[kw][0][1][qw * 32 + s * 8][0]);
  }
  __syncthreads();

#pragma unroll 2
  for (int t = 0; t < 16; ++t) {
    const int cur = t & 1, nxt = cur ^ 1;
    // stage next 64-key tile (lands during this iter's compute; barrier drains)
    if (t < 15) {
      const int kt = (t + 1) * 64;
#pragma unroll
      for (int s = 0; s < 4; s++) {
        load16(Kbase + (size_t)(kt + s * 8) * DM, &KVt[kw][nxt][0][qw * 32 + s * 8][0]);
        load16(Vbase + (size_t)(s * 8) * SEQ + kt, &KVt[kw][nxt][1][qw * 32 + s * 8][0]);
      }
    }
    // compute on current tile: 64 keys = 2 x 32-key kh phases
#pragma unroll
    for (int kh = 0; kh < 2; kh++) {
      const int rk = kh * 32 + l31;
      bf16x8 kf[4];
#pragma unroll
      for (int dc = 0; dc < 4; dc++)
        kf[dc] = *(const bf16x8*)&KVt[kw][cur][0][rk][((dc * 2 + hi) ^ (rk & 7)) * 8];
      // ---- V frags issued BEFORE QK: ds_read latency hides under MFMA ----
      bf16x8 vfA0 = *(const bf16x8*)&KVt[kw][cur][1][l31     ][((kh * 4 + hi) ^ (l31 & 7)) * 8];
      bf16x8 vfA1 = *(const bf16x8*)&KVt[kw][cur][1][32 + l31][((kh * 4 + hi) ^ (l31 & 7)) * 8];
      bf16x8 vfB0 = *(const bf16x8*)&KVt[kw][cur][1][l31     ][((kh * 4 + 2 + hi) ^ (l31 & 7)) * 8];
      bf16x8 vfB1 = *(const bf16x8*)&KVt[kw][cur][1][32 + l31][((kh * 4 + 2 + hi) ^ (l31 & 7)) * 8];
      // ---- QK^T for both q-tiles (two independent chains) ----
      floatx16 z0 = zf16, z1 = zf16;
      __builtin_amdgcn_s_setprio(1);
#pragma unroll
      for (int dc = 0; dc < 4; dc++) {
        z0 = mfma32(kf[dc], qf0[dc], z0);
        z1 = mfma32(kf[dc], qf1[dc], z1);
      }
      __builtin_amdgcn_s_setprio(0);
      // ---- q-tile 0: softmax + PV ----
      {
        float p0 = EXP2(z0[0]), p1 = EXP2(z0[1]), p2 = EXP2(z0[2]), p3 = EXP2(z0[3]);
        float p4 = EXP2(z0[4]), p5 = EXP2(z0[5]), p6 = EXP2(z0[6]), p7 = EXP2(z0[7]);
        float p8 = EXP2(z0[8]),  p9 = EXP2(z0[9]),  pa = EXP2(z0[10]), pb = EXP2(z0[11]);
        float pc = EXP2(z0[12]), pd = EXP2(z0[13]), pe = EXP2(z0[14]), pf = EXP2(z0[15]);
        ls0 += (((p0 + p1) + (p2 + p3)) + ((p4 + p5) + (p6 + p7)))
             + (((p8 + p9) + (pa + pb)) + ((pc + pd) + (pe + pf)));
        bf16x8 bA = packex(p0, p1, p2, p3, p4, p5, p6, p7, hi);
        bf16x8 bB = packex(p8, p9, pa, pb, pc, pd, pe, pf, hi);
        __builtin_amdgcn_s_setprio(1);
        o00 = mfma32(vfA0, bA, o00);
        o01 = mfma32(vfA1, bA, o01);
        o00 = mfma32(vfB0, bB, o00);
        o01 = mfma32(vfB1, bB, o01);
        __builtin_amdgcn_s_setprio(0);
      }
      // ---- q-tile 1: softmax + PV ----
      {
        float p0 = EXP2(z1[0]), p1 = EXP2(z1[1]), p2 = EXP2(z1[2]), p3 = EXP2(z1[3]);
        float p4 = EXP2(z1[4]), p5 = EXP2(z1[5]), p6 = EXP2(z1[6]), p7 = EXP2(z1[7]);
        float p8 = EXP2(z1[8]),  p9 = EXP2(z1[9]),  pa = EXP2(z1[10]), pb = EXP2(z1[11]);
        float pc = EXP2(z1[12]), pd = EXP2(z1[13]), pe = EXP2(z1[14]), pf = EXP2(z1[15]);
        ls1 += (((p0 + p1) + (p2 + p3)) + ((p4 + p5) + (p6 + p7)))
             + (((p8 + p9) + (pa + pb)) + ((pc + pd) + (pe + pf)));
        bf16x8 bA = packex(p0, p1, p2, p3, p4, p5, p6, p7, hi);
        bf16x8 bB = packex(p8, p9, pa, pb, pc, pd, pe, pf, hi);
        __builtin_amdgcn_s_setprio(1);
        o10 = mfma32(vfA0, bA, o10);
        o11 = mfma32(vfA1, bA, o11);
        o10 = mfma32(vfB0, bB, o10);
        o11 = mfma32(vfB1, bB, o11);
        __builtin_amdgcn_s_setprio(0);
      }
    }
    __syncthreads();   // next tile landed (vmcnt drain) + cur free for overwrite
  }

  // ---- 2-way key-half combine through LDS (reuse KVt; all compute done) ----
  float* Osh = (float*)&KVt[0][0][0][0][0];   // [128 q][68 d-padded] + L[128]
  float* Lsh = Osh + 128 * 68;
  const float lsum0 = ls0 + __shfl_xor(ls0, 32);
  const float lsum1 = ls1 + __shfl_xor(ls1, 32);
  const int qA = qw * 64 + l31;        // q-tile 0 row
  const int qB = qw * 64 + 32 + l31;   // q-tile 1 row
  if (kw == 1) {
#pragma unroll
    for (int g = 0; g < 4; g++) {
      *(floatx4*)&Osh[qA * 68 +      g * 8 + hi * 4] =
          (floatx4){o00[4*g], o00[4*g+1], o00[4*g+2], o00[4*g+3]};
      *(floatx4*)&Osh[qA * 68 + 32 + g * 8 + hi * 4] =
          (floatx4){o01[4*g], o01[4*g+1], o01[4*g+2], o01[4*g+3]};
      *(floatx4*)&Osh[qB * 68 +      g * 8 + hi * 4] =
          (floatx4){o10[4*g], o10[4*g+1], o10[4*g+2], o10[4*g+3]};
      *(floatx4*)&Osh[qB * 68 + 32 + g * 8 + hi * 4] =
          (floatx4){o11[4*g], o11[4*g+1], o11[4*g+2], o11[4*g+3]};
    }
    if (hi == 0) { Lsh[qA] = lsum0; Lsh[qB] = lsum1; }
  }
  __syncthreads();
  if (kw == 0) {
    const float inv0 = 1.f / (lsum0 + Lsh[qA]);
    const float inv1 = 1.f / (lsum1 + Lsh[qB]);
    u16* CrowA = CTX + (size_t)(b * SEQ + q0 + qA) * DM + h * HD + hi * 4;
    u16* CrowB = CTX + (size_t)(b * SEQ + q0 + qB) * DM + h * HD + hi * 4;
#pragma unroll
    for (int g = 0; g < 4; g++) {
      const float* ocA0 = &Osh[qA * 68 +      g * 8 + hi * 4];
      const float* ocA1 = &Osh[qA * 68 + 32 + g * 8 + hi * 4];
      const float* ocB0 = &Osh[qB * 68 +      g * 8 + hi * 4];
      const float* ocB1 = &Osh[qB * 68 + 32 + g * 8 + hi * 4];
      union { u16 u[4]; uint2 w2; } t0, t1, t2, t3;
#pragma unroll
      for (int r = 0; r < 4; r++) {
        t0.u[r] = f2bf((o00[4*g+r] + ocA0[r]) * inv0);
        t1.u[r] = f2bf((o01[4*g+r] + ocA1[r]) * inv0);
        t2.u[r] = f2bf((o10[4*g+r] + ocB0[r]) * inv1);
        t3.u[r] = f2bf((o11[4*g+r] + ocB1[r]) * inv1);
      }
      *(uint2*)(CrowA +      g * 8) = t0.w2;
      *(uint2*)(CrowA + 32 + g * 8) = t1.w2;
      *(uint2*)(CrowB +      g * 8) = t2.w2;
      *(uint2*)(CrowB + 32 + g * 8) = t3.w2;
    }
  }
}

// ---------------- launch ----------------
extern "C" void kernel_launch(void* const* d_in, const int* in_sizes, int n_in,
                              void* d_out, int out_size, void* d_ws, size_t ws_size,
                              hipStream_t stream) {
  const float* x   = (const float*)d_in[0];
  const float* Wq  = (const float*)d_in[1];
  const float* bq  = (const float*)d_in[2];
  const float* Wkd = (const float*)d_in[3];
  const float* bkd = (const float*)d_in[4];
  const float* Wvd = (const float*)d_in[5];
  const float* bvd = (const float*)d_in[6];
  const float* Wku = (const float*)d_in[7];
  const float* bku = (const float*)d_in[8];
  const float* Wvu = (const float*)d_in[9];
  const float* bvu = (const float*)d_in[10];
  const float* Wo  = (const float*)d_in[11];
  const float* bo  = (const float*)d_in[12];
  float* out = (float*)d_out;

  float* bqkv = (float*)d_ws;
  u16* p = (u16*)((char*)d_ws + 1536 * sizeof(float));
  u16* xb    = p; p += (size_t)MTOT * DM;
  u16* WstkT = p; p += (size_t)NQKV * DM;           // WqT | WkdT | WvdT
  u16* WkuT  = p; p += (size_t)DM * LAT;
  u16* WvuT  = p; p += (size_t)DM * LAT;
  u16* WoT   = p; p += (size_t)DM * DM;
  u16* QKVb  = p; p += (size_t)MTOT * NQKV;         // Q(pre-scaled) | KL | VL
  u16* Kb    = p; p += (size_t)MTOT * DM;
  u16* VTb   = p; p += (size_t)MTOT * DM;
  u16* CXb   = p; p += (size_t)MTOT * DM;

  prep_k<<<4870, 256, 0, stream>>>(x, xb, Wq, Wkd, Wvd, Wku, Wvu, Wo,
                                   WstkT, WkuT, WvuT, WoT, bq, bkd, bvd, bqkv);

  // QKV projection: 128x128 tiles -> 12x32 = 384 blocks
  gemm_bt<128, 128, 1, 0><<<dim3(NQKV / 128, MTOT / 128, 1), 256, 0, stream>>>(
      xb, xb, WstkT, WstkT, bqkv, bqkv, QKVb, QKVb, MTOT, NQKV, DM, DM, QSCALE, DM);
  // K-up (row layout) + V-up (transposed layout): K=256 -> keep 128x64, 16x32x2
  gemm_bt<128, 64, 1, 1><<<dim3(DM / 64, MTOT / 128, 2), 256, 0, stream>>>(
      QKVb + 1024, QKVb + 1280, WkuT, WvuT, bku, bvu, Kb, VTb, MTOT, DM, LAT, NQKV, 1.f, 0);

  // 512 blocks x 256 threads: 16 q-blocks x 32 bh, XCD-remapped inside
  attn_fused<<<dim3(SEQ / 128, B_SZ * NH), 256, 0, stream>>>(QKVb, Kb, VTb, CXb);

  // output projection: 128x128 tiles -> 8x32 = 256 blocks
  gemm_bt<128, 128, 0, 0><<<dim3(DM / 128, MTOT / 128, 1), 256, 0, stream>>>(
      CXb, CXb, WoT, WoT, bo, bo, out, out, MTOT, DM, DM, DM, 1.f, 0);
}

// Round 11
// 198.973 us; speedup vs baseline: 1.0480x; 1.0480x over previous
//
#include <hip/hip_runtime.h>
#include <hip/hip_bf16.h>
#include <cstddef>

#define B_SZ 2
#define SEQ  2048
#define DM   1024
#define NH   16
#define HD   64
#define LAT  256
#define MTOT (B_SZ*SEQ)   // 4096
#define NQKV 1536
#define QSCALE 0.18033688011112042f  // 0.125 * log2(e)

typedef short bf16x8 __attribute__((ext_vector_type(8)));
typedef float floatx4 __attribute__((ext_vector_type(4)));
typedef float floatx16 __attribute__((ext_vector_type(16)));
typedef unsigned short u16;
typedef unsigned uintx2 __attribute__((ext_vector_type(2)));

#if __has_builtin(__builtin_amdgcn_exp2f)
#define EXP2(x) __builtin_amdgcn_exp2f(x)
#else
#define EXP2(x) exp2f(x)
#endif

__device__ __forceinline__ u16 f2bf(float f) {
  union { float f; unsigned u; } a; a.f = f;
  unsigned r = a.u + 0x7FFFu + ((a.u >> 16) & 1u);  // RNE
  return (u16)(r >> 16);
}

__device__ __forceinline__ floatx4 mfma16(bf16x8 a, bf16x8 b, floatx4 c) {
  return __builtin_amdgcn_mfma_f32_16x16x32_bf16(a, b, c, 0, 0, 0);
}

__device__ __forceinline__ floatx16 mfma32(bf16x8 a, bf16x8 b, floatx16 c) {
  return __builtin_amdgcn_mfma_f32_32x32x16_bf16(a, b, c, 0, 0, 0);
}

// async global->LDS, 16B per lane; lds dest = wave-uniform base + lane*16
__device__ __forceinline__ void load16(const u16* g, u16* l) {
  __builtin_amdgcn_global_load_lds((const __attribute__((address_space(1))) unsigned*)g,
                                   (__attribute__((address_space(3))) unsigned*)l, 16, 0, 0);
}

// pack 8 probs to bf16 pairs + lane-half exchange -> PV B-operand (m74/m101 map).
// permlane32_swap (VALU) replaces ds_bpermute (LDS pipe) [T12]: R7->R8 55.3->49.3us.
__device__ __forceinline__ bf16x8 packex(float p0, float p1, float p2, float p3,
                                         float p4, float p5, float p6, float p7, int hi) {
  unsigned w0 = __builtin_amdgcn_perm(__float_as_uint(p1) + 0x8000u,
                                      __float_as_uint(p0) + 0x8000u, 0x07060302u);
  unsigned w1 = __builtin_amdgcn_perm(__float_as_uint(p3) + 0x8000u,
                                      __float_as_uint(p2) + 0x8000u, 0x07060302u);
  unsigned w2 = __builtin_amdgcn_perm(__float_as_uint(p5) + 0x8000u,
                                      __float_as_uint(p4) + 0x8000u, 0x07060302u);
  unsigned w3 = __builtin_amdgcn_perm(__float_as_uint(p7) + 0x8000u,
                                      __float_as_uint(p6) + 0x8000u, 0x07060302u);
  union { unsigned u[4]; bf16x8 v; } bb;
#if __has_builtin(__builtin_amdgcn_permlane32_swap)
  uintx2 r02 = __builtin_amdgcn_permlane32_swap(w0, w2, false, false);
  uintx2 r13 = __builtin_amdgcn_permlane32_swap(w1, w3, false, false);
  bb.u[0] = r02.x; bb.u[1] = r13.x; bb.u[2] = r02.y; bb.u[3] = r13.y;
#else
  unsigned s0 = (unsigned)__shfl_xor((int)w0, 32);
  unsigned s1 = (unsigned)__shfl_xor((int)w1, 32);
  unsigned s2 = (unsigned)__shfl_xor((int)w2, 32);
  unsigned s3 = (unsigned)__shfl_xor((int)w3, 32);
  bb.u[0] = hi ? s2 : w0;
  bb.u[1] = hi ? s3 : w1;
  bb.u[2] = hi ? w2 : s0;
  bb.u[3] = hi ? w3 : s1;
#endif
  return bb.v;
}

// ---------------- mega prep: cast x | 6 weight transposes | bias concat ----------------
__device__ void transpose_tile(const float* __restrict__ W, u16* __restrict__ WT,
                               int K, int N, int k0, int n0, u16 (*t)[65]) {
  const int r = threadIdx.x >> 4;          // 0..15
  const int c4 = (threadIdx.x & 15) * 4;   // 0..60
#pragma unroll
  for (int s = 0; s < 4; s++) {
    int row = s * 16 + r;
    float4 v = *(const float4*)&W[(size_t)(k0 + row) * N + n0 + c4];
    t[row][c4 + 0] = f2bf(v.x); t[row][c4 + 1] = f2bf(v.y);
    t[row][c4 + 2] = f2bf(v.z); t[row][c4 + 3] = f2bf(v.w);
  }
  __syncthreads();
  const int r2 = threadIdx.x >> 2;          // 0..63 (out row = n)
  const int c8 = (threadIdx.x & 3) * 16;    // 0,16,32,48 (out col = k)
  __align__(16) u16 tmp[16];
#pragma unroll
  for (int i = 0; i < 16; i++) tmp[i] = t[c8 + i][r2];
  u16* dst = WT + (size_t)(n0 + r2) * K + k0 + c8;
  *(bf16x8*)dst       = *(const bf16x8*)&tmp[0];
  *(bf16x8*)(dst + 8) = *(const bf16x8*)&tmp[8];
}

__global__ __launch_bounds__(256)
void prep_k(const float* __restrict__ x, u16* __restrict__ xb,
            const float* __restrict__ Wq, const float* __restrict__ Wkd,
            const float* __restrict__ Wvd, const float* __restrict__ Wku,
            const float* __restrict__ Wvu, const float* __restrict__ Wo,
            u16* __restrict__ WstkT, u16* __restrict__ WkuT,
            u16* __restrict__ WvuT, u16* __restrict__ WoT,
            const float* __restrict__ bq, const float* __restrict__ bkd,
            const float* __restrict__ bvd, float* __restrict__ bqkv) {
  __shared__ u16 t[64][65];
  const int blk = blockIdx.x;
  if (blk < 4096) {                 // cast x -> bf16, 1 float4/thread
    int i = blk * 256 + threadIdx.x;
    float4 v = ((const float4*)x)[i];
    ushort4 o; o.x = f2bf(v.x); o.y = f2bf(v.y); o.z = f2bf(v.z); o.w = f2bf(v.w);
    ((ushort4*)xb)[i] = o;
  } else if (blk < 4352) {          // Wq^T -> WstkT[0:1024]
    int tt = blk - 4096;
    transpose_tile(Wq, WstkT, DM, DM, (tt >> 4) * 64, (tt & 15) * 64, t);
  } else if (blk < 4416) {          // Wkd^T -> WstkT[1024:1280]
    int tt = blk - 4352;
    transpose_tile(Wkd, WstkT + (size_t)DM * DM, DM, LAT, (tt >> 2) * 64, (tt & 3) * 64, t);
  } else if (blk < 4480) {          // Wvd^T -> WstkT[1280:1536]
    int tt = blk - 4416;
    transpose_tile(Wvd, WstkT + (size_t)1280 * DM, DM, LAT, (tt >> 2) * 64, (tt & 3) * 64, t);
  } else if (blk < 4544) {          // Wku^T
    int tt = blk - 4480;
    transpose_tile(Wku, WkuT, LAT, DM, (tt >> 4) * 64, (tt & 15) * 64, t);
  } else if (blk < 4608) {          // Wvu^T
    int tt = blk - 4544;
    transpose_tile(Wvu, WvuT, LAT, DM, (tt >> 4) * 64, (tt & 15) * 64, t);
  } else if (blk < 4864) {          // Wo^T
    int tt = blk - 4608;
    transpose_tile(Wo, WoT, DM, DM, (tt >> 4) * 64, (tt & 15) * 64, t);
  } else {                          // bias concat (6 blocks)
    int i = (blk - 4864) * 256 + threadIdx.x;
    float v = (i < 1024) ? bq[i] : (i < 1280) ? bkd[i - 1024] : bvd[i - 1280];
    bqkv[i] = v;
  }
}

// ---------------- GEMM: C = A * BT^T + bias ----------------
// R11: REVERTED to 128x64 tiles everywhere (R10's 128x128 cost +10us: grid
// shrank to 1-1.5 blocks/CU, killing the co-residency that actually hides
// staging [R9 finding]; big-tile wins assume huge grids). Keeps R9's 2-phase
// 1-barrier k-loop (neutral-not-harmful). Non-attn cost is stable ~145-150us
// across 0-phase/2-phase/big-tile -> GEMMs are latency/overhead-bound at ~30%
// MfmaUtil (floor ~25us total); cheap structural levers exhausted.
template<int TM, int TN, int OUT_BF16, int VT1>
__global__ __launch_bounds__(256)
void gemm_bt(const u16* __restrict__ A0, const u16* __restrict__ A1,
             const u16* __restrict__ BT0, const u16* __restrict__ BT1,
             const float* __restrict__ bias0, const float* __restrict__ bias1,
             void* __restrict__ C0, void* __restrict__ C1,
             int M, int N, int Kd, int lda, float qscale, int qcols) {
  constexpr int FI = TM / 32;       // A-frags per wave along M (wave tile TM/2)
  constexpr int FJ = TN / 32;       // B-frags per wave along N (wave tile TN/2)
  __shared__ u16 As[2][TM * 64];
  __shared__ u16 Bs[2][TN * 64];
  const u16* A  = blockIdx.z ? A1 : A0;
  const u16* BT = blockIdx.z ? BT1 : BT0;
  const float* bias = blockIdx.z ? bias1 : bias0;
  void* C = blockIdx.z ? C1 : C0;

  const int tid = threadIdx.x;
  const int m0 = blockIdx.y * TM, n0 = blockIdx.x * TN;
  const int wave = tid >> 6, lane = tid & 63;
  const int l15 = lane & 15, quad = lane >> 4;
  const int wm = (wave >> 1) * (TM / 2), wn = (wave & 1) * (TN / 2);

  floatx4 acc[FI][FJ];
#pragma unroll
  for (int i = 0; i < FI; i++)
#pragma unroll
    for (int j = 0; j < FJ; j++) acc[i][j] = (floatx4){0.f, 0.f, 0.f, 0.f};

  const int tr = tid >> 3;          // 0..31
  const int tc8 = (tid & 7) * 8;
  const u16* Ag = A  + (size_t)(m0 + tr) * lda + tc8;
  const u16* Bg = BT + (size_t)(n0 + tr) * Kd + tc8;

  // stage 64-K slab k0 into buffer buf
  auto stage = [&](int k0, int buf) {
#pragma unroll
    for (int s = 0; s < TM / 32; s++)
      load16(Ag + (size_t)(s * 32) * lda + k0, &As[buf][(size_t)tid * 8 + s * 2048]);
#pragma unroll
    for (int s = 0; s < TN / 32; s++)
      load16(Bg + (size_t)(s * 32) * Kd  + k0, &Bs[buf][(size_t)tid * 8 + s * 2048]);
  };

  stage(0, 0);
  __syncthreads();                  // vmcnt(0) drain: buf0 ready

  int buf = 0;
  for (int k0 = 0; k0 < Kd; k0 += 64, buf ^= 1) {
    if (k0 + 64 < Kd) stage(k0 + 64, buf ^ 1);   // async, overlaps compute below
#pragma unroll
    for (int kk = 0; kk < 2; kk++) {
      bf16x8 af[FI], bfr[FJ];
#pragma unroll
      for (int i = 0; i < FI; i++)
        af[i]  = *(const bf16x8*)&As[buf][(wm + i * 16 + l15) * 64 + kk * 32 + quad * 8];
#pragma unroll
      for (int j = 0; j < FJ; j++)
        bfr[j] = *(const bf16x8*)&Bs[buf][(wn + j * 16 + l15) * 64 + kk * 32 + quad * 8];
#pragma unroll
      for (int i = 0; i < FI; i++)
#pragma unroll
        for (int j = 0; j < FJ; j++)
          acc[i][j] = mfma16(af[i], bfr[j], acc[i][j]);
    }
    __syncthreads();                // drains k+1 loads + frees buf for overwrite
  }

  if (VT1 && blockIdx.z == 1) {
    // write V in transposed per-head layout: VT[(b*16+h)*64+d][s]
#pragma unroll
    for (int i = 0; i < FI; i++) {
      int row = m0 + wm + i * 16 + quad * 4;    // b*2048 + s (s ≡ 0 mod 4)
      int bb = row >> 11, sb = row & 2047;
#pragma unroll
      for (int j = 0; j < FJ; j++) {
        int col = n0 + wn + j * 16 + l15;       // h*64 + d
        float bv = bias[col];
        union { u16 u[4]; uint2 w2; } tv;
#pragma unroll
        for (int r = 0; r < 4; r++) tv.u[r] = f2bf(acc[i][j][r] + bv);
        *(uint2*)((u16*)C + ((size_t)(bb * 16 + (col >> 6)) * 64 + (col & 63)) * SEQ + sb) = tv.w2;
      }
    }
  } else {
#pragma unroll
    for (int i = 0; i < FI; i++) {
      int row = m0 + wm + i * 16 + quad * 4;
#pragma unroll
      for (int j = 0; j < FJ; j++) {
        int col = n0 + wn + j * 16 + l15;
        float bv = bias[col];
        float sc = (col < qcols) ? qscale : 1.f;
#pragma unroll
        for (int r = 0; r < 4; r++) {
          float v = (acc[i][j][r] + bv) * sc;
          if (OUT_BF16) ((u16*)C)[(size_t)(row + r) * N + col] = f2bf(v);
          else          ((float*)C)[(size_t)(row + r) * N + col] = v;
        }
      }
    }
  }
}

// ---------------- fused attention (cross-phase ILP: QK0,QK1 then 4x SM->PV) ----------------
// R10 state: 50us vs ~21us pipe-max floor; MFMA 27%, VALU 39%, LDS ~33% — NO
// pipe saturated -> latency/overlap regime (rule #23: R6's TLP-null was in the
// pre-R7 LDS-saturated regime, doesn't gate here). The t-iter was a serial
// chain QK0->SM0->PV0->QK1->SM1->PV1: MFMA and VALU pipes alternate, each idle
// ~half the time. R11: issue BOTH QK phases first (QK1's 8 independent MFMAs
// fill QK0's chain-tail bubble), then 4x (SM->PV): each PV's MFMA cluster
// overlaps the NEXT SM's exp2/pack VALU stretch (no data deps; scheduler
// interleaves). Accumulation order per o/ls unchanged -> bit-identical.
// Reg peak est ~215 (z x4 = 64 live f32) inside the 256 bucket at waves=2.
// Spill alarm: WRITE_SIZE >> 8.2MB or VGPR pinned at 256 [R4 lesson].
__global__ __launch_bounds__(256, 2)
void attn_fused(const u16* __restrict__ Q, const u16* __restrict__ K,
                const u16* __restrict__ VT, u16* __restrict__ CTX) {
  __shared__ __align__(16) u16 KVt[2][2][2][64][64];  // [kw][buf][K/V][row][64] = 64 KiB
  const int lin = blockIdx.y * gridDim.x + blockIdx.x;
  const int idx = lin >> 3;
  const int bh = (lin & 7) * 4 + (idx >> 4);   // XCD (lin%8) owns bh group of 4
  const int q0 = (idx & 15) * 128;
  const int b = bh >> 4, h = bh & 15;
  const int wave = threadIdx.x >> 6, lane = threadIdx.x & 63;
  const int qw = wave & 1;                     // q sub-tile pair 0..1 (64 rows each)
  const int kw = wave >> 1;                    // key half 0/1
  const int l31 = lane & 31;
  const int hi = lane >> 5;                    // lane half: 0/1
  const int lr = lane >> 3;                    // staging row-within-8 (0..7)
  const int cx = (lane & 7) ^ lr;              // pre-swizzled source chunk

  // Q as B-operand for 2 q-tiles: qf{0,1}[dc] = Q[q0+qw*64+qt*32+l31][h*64+dc*16+hi*8+j]
  bf16x8 qf0[4], qf1[4];
  {
    const u16* Qp = Q + (size_t)(b * SEQ + q0 + qw * 64 + l31) * NQKV + h * HD + hi * 8;
#pragma unroll
    for (int dc = 0; dc < 4; dc++) {
      qf0[dc] = *(const bf16x8*)(Qp + dc * 16);
      qf1[dc] = *(const bf16x8*)(Qp + (size_t)32 * NQKV + dc * 16);
    }
  }

  // staging sources (pre-swizzled): wave stages rows [qw*32, qw*32+32) of its
  // kw-half tile, via 4 instr K + 4 instr V (8 rows each).
  const u16* Kbase = K + (size_t)(b * SEQ + kw * 1024 + qw * 32 + lr) * DM + h * HD + cx * 8;
  const u16* Vbase = VT + ((size_t)bh * HD + qw * 32 + lr) * SEQ + kw * 1024 + cx * 8;

  floatx16 o00, o01, o10, o11;   // o[qt][dh]: ctx^T 32x32 tiles (row d, col q=l31)
  const floatx16 zf16 = {0.f,0.f,0.f,0.f,0.f,0.f,0.f,0.f,0.f,0.f,0.f,0.f,0.f,0.f,0.f,0.f};
  o00 = zf16; o01 = zf16; o10 = zf16; o11 = zf16;
  float ls0 = 0.f, ls1 = 0.f;

  // SM -> PV for one 32-key z-tile: exp2+rowsum+pack, then 4 PV MFMAs.
  auto smpv = [&](floatx16& zz, bf16x8 v0, bf16x8 v1, bf16x8 v2, bf16x8 v3,
                  floatx16& oa, floatx16& ob, float& lss) {
    float p0 = EXP2(zz[0]), p1 = EXP2(zz[1]), p2 = EXP2(zz[2]), p3 = EXP2(zz[3]);
    float p4 = EXP2(zz[4]), p5 = EXP2(zz[5]), p6 = EXP2(zz[6]), p7 = EXP2(zz[7]);
    float p8 = EXP2(zz[8]),  p9 = EXP2(zz[9]),  pa = EXP2(zz[10]), pb = EXP2(zz[11]);
    float pc = EXP2(zz[12]), pd = EXP2(zz[13]), pe = EXP2(zz[14]), pf = EXP2(zz[15]);
    lss += (((p0 + p1) + (p2 + p3)) + ((p4 + p5) + (p6 + p7)))
         + (((p8 + p9) + (pa + pb)) + ((pc + pd) + (pe + pf)));
    bf16x8 bA = packex(p0, p1, p2, p3, p4, p5, p6, p7, hi);
    bf16x8 bB = packex(p8, p9, pa, pb, pc, pd, pe, pf, hi);
    __builtin_amdgcn_s_setprio(1);
    oa = mfma32(v0, bA, oa);
    ob = mfma32(v1, bA, ob);
    oa = mfma32(v2, bB, oa);
    ob = mfma32(v3, bB, ob);
    __builtin_amdgcn_s_setprio(0);
  };

  // prologue: stage tile 0 into buf 0 of this kw half
#pragma unroll
  for (int s = 0; s < 4; s++) {
    load16(Kbase + (size_t)(s * 8) * DM, &KVt[kw][0][0][qw * 32 + s * 8][0]);
    load16(Vbase + (size_t)(s * 8) * SEQ, &KVt[kw][0][1][qw * 32 + s * 8][0]);
  }
  __syncthreads();

#pragma unroll 2
  for (int t = 0; t < 16; ++t) {
    const int cur = t & 1, nxt = cur ^ 1;
    // stage next 64-key tile (lands during this iter's compute; barrier drains)
    if (t < 15) {
      const int kt = (t + 1) * 64;
#pragma unroll
      for (int s = 0; s < 4; s++) {
        load16(Kbase + (size_t)(kt + s * 8) * DM, &KVt[kw][nxt][0][qw * 32 + s * 8][0]);
        load16(Vbase + (size_t)(s * 8) * SEQ + kt, &KVt[kw][nxt][1][qw * 32 + s * 8][0]);
      }
    }
    // ---- all V frags for this tile (8 reads; latency hides under QK MFMAs) ----
    bf16x8 vf[2][4];   // [kh][{A0,A1,B0,B1}]
#pragma unroll
    for (int kh = 0; kh < 2; kh++) {
      vf[kh][0] = *(const bf16x8*)&KVt[kw][cur][1][l31     ][((kh * 4 + hi) ^ (l31 & 7)) * 8];
      vf[kh][1] = *(const bf16x8*)&KVt[kw][cur][1][32 + l31][((kh * 4 + hi) ^ (l31 & 7)) * 8];
      vf[kh][2] = *(const bf16x8*)&KVt[kw][cur][1][l31     ][((kh * 4 + 2 + hi) ^ (l31 & 7)) * 8];
      vf[kh][3] = *(const bf16x8*)&KVt[kw][cur][1][32 + l31][((kh * 4 + 2 + hi) ^ (l31 & 7)) * 8];
    }
    // ---- QK^T kh=0 (z00,z01) then kh=1 (z10,z11): 16 MFMAs back-to-back ----
    floatx16 z00 = zf16, z01 = zf16, z10 = zf16, z11 = zf16;
    {
      bf16x8 kf[4];
#pragma unroll
      for (int dc = 0; dc < 4; dc++)
        kf[dc] = *(const bf16x8*)&KVt[kw][cur][0][l31][((dc * 2 + hi) ^ (l31 & 7)) * 8];
      __builtin_amdgcn_s_setprio(1);
#pragma unroll
      for (int dc = 0; dc < 4; dc++) {
        z00 = mfma32(kf[dc], qf0[dc], z00);
        z01 = mfma32(kf[dc], qf1[dc], z01);
      }
      __builtin_amdgcn_s_setprio(0);
#pragma unroll
      for (int dc = 0; dc < 4; dc++)
        kf[dc] = *(const bf16x8*)&KVt[kw][cur][0][32 + l31][((dc * 2 + hi) ^ (l31 & 7)) * 8];
      __builtin_amdgcn_s_setprio(1);
#pragma unroll
      for (int dc = 0; dc < 4; dc++) {
        z10 = mfma32(kf[dc], qf0[dc], z10);
        z11 = mfma32(kf[dc], qf1[dc], z11);
      }
      __builtin_amdgcn_s_setprio(0);
    }
    // ---- 4x (SM -> PV): each PV MFMA cluster overlaps the next SM's VALU ----
    smpv(z00, vf[0][0], vf[0][1], vf[0][2], vf[0][3], o00, o01, ls0);
    smpv(z01, vf[0][0], vf[0][1], vf[0][2], vf[0][3], o10, o11, ls1);
    smpv(z10, vf[1][0], vf[1][1], vf[1][2], vf[1][3], o00, o01, ls0);
    smpv(z11, vf[1][0], vf[1][1], vf[1][2], vf[1][3], o10, o11, ls1);
    __syncthreads();   // next tile landed (vmcnt drain) + cur free for overwrite
  }

  // ---- 2-way key-half combine through LDS (reuse KVt; all compute done) ----
  float* Osh = (float*)&KVt[0][0][0][0][0];   // [128 q][68 d-padded] + L[128]
  float* Lsh = Osh + 128 * 68;
  const float lsum0 = ls0 + __shfl_xor(ls0, 32);
  const float lsum1 = ls1 + __shfl_xor(ls1, 32);
  const int qA = qw * 64 + l31;        // q-tile 0 row
  const int qB = qw * 64 + 32 + l31;   // q-tile 1 row
  if (kw == 1) {
#pragma unroll
    for (int g = 0; g < 4; g++) {
      *(floatx4*)&Osh[qA * 68 +      g * 8 + hi * 4] =
          (floatx4){o00[4*g], o00[4*g+1], o00[4*g+2], o00[4*g+3]};
      *(floatx4*)&Osh[qA * 68 + 32 + g * 8 + hi * 4] =
          (floatx4){o01[4*g], o01[4*g+1], o01[4*g+2], o01[4*g+3]};
      *(floatx4*)&Osh[qB * 68 +      g * 8 + hi * 4] =
          (floatx4){o10[4*g], o10[4*g+1], o10[4*g+2], o10[4*g+3]};
      *(floatx4*)&Osh[qB * 68 + 32 + g * 8 + hi * 4] =
          (floatx4){o11[4*g], o11[4*g+1], o11[4*g+2], o11[4*g+3]};
    }
    if (hi == 0) { Lsh[qA] = lsum0; Lsh[qB] = lsum1; }
  }
  __syncthreads();
  if (kw == 0) {
    const float inv0 = 1.f / (lsum0 + Lsh[qA]);
    const float inv1 = 1.f / (lsum1 + Lsh[qB]);
    u16* CrowA = CTX + (size_t)(b * SEQ + q0 + qA) * DM + h * HD + hi * 4;
    u16* CrowB = CTX + (size_t)(b * SEQ + q0 + qB) * DM + h * HD + hi * 4;
#pragma unroll
    for (int g = 0; g < 4; g++) {
      const float* ocA0 = &Osh[qA * 68 +      g * 8 + hi * 4];
      const float* ocA1 = &Osh[qA * 68 + 32 + g * 8 + hi * 4];
      const float* ocB0 = &Osh[qB * 68 +      g * 8 + hi * 4];
      const float* ocB1 = &Osh[qB * 68 + 32 + g * 8 + hi * 4];
      union { u16 u[4]; uint2 w2; } t0, t1, t2, t3;
#pragma unroll
      for (int r = 0; r < 4; r++) {
        t0.u[r] = f2bf((o00[4*g+r] + ocA0[r]) * inv0);
        t1.u[r] = f2bf((o01[4*g+r] + ocA1[r]) * inv0);
        t2.u[r] = f2bf((o10[4*g+r] + ocB0[r]) * inv1);
        t3.u[r] = f2bf((o11[4*g+r] + ocB1[r]) * inv1);
      }
      *(uint2*)(CrowA +      g * 8) = t0.w2;
      *(uint2*)(CrowA + 32 + g * 8) = t1.w2;
      *(uint2*)(CrowB +      g * 8) = t2.w2;
      *(uint2*)(CrowB + 32 + g * 8) = t3.w2;
    }
  }
}

// ---------------- launch ----------------
extern "C" void kernel_launch(void* const* d_in, const int* in_sizes, int n_in,
                              void* d_out, int out_size, void* d_ws, size_t ws_size,
                              hipStream_t stream) {
  const float* x   = (const float*)d_in[0];
  const float* Wq  = (const float*)d_in[1];
  const float* bq  = (const float*)d_in[2];
  const float* Wkd = (const float*)d_in[3];
  const float* bkd = (const float*)d_in[4];
  const float* Wvd = (const float*)d_in[5];
  const float* bvd = (const float*)d_in[6];
  const float* Wku = (const float*)d_in[7];
  const float* bku = (const float*)d_in[8];
  const float* Wvu = (const float*)d_in[9];
  const float* bvu = (const float*)d_in[10];
  const float* Wo  = (const float*)d_in[11];
  const float* bo  = (const float*)d_in[12];
  float* out = (float*)d_out;

  float* bqkv = (float*)d_ws;
  u16* p = (u16*)((char*)d_ws + 1536 * sizeof(float));
  u16* xb    = p; p += (size_t)MTOT * DM;
  u16* WstkT = p; p += (size_t)NQKV * DM;           // WqT | WkdT | WvdT
  u16* WkuT  = p; p += (size_t)DM * LAT;
  u16* WvuT  = p; p += (size_t)DM * LAT;
  u16* WoT   = p; p += (size_t)DM * DM;
  u16* QKVb  = p; p += (size_t)MTOT * NQKV;         // Q(pre-scaled) | KL | VL
  u16* Kb    = p; p += (size_t)MTOT * DM;
  u16* VTb   = p; p += (size_t)MTOT * DM;
  u16* CXb   = p; p += (size_t)MTOT * DM;

  prep_k<<<4870, 256, 0, stream>>>(x, xb, Wq, Wkd, Wvd, Wku, Wvu, Wo,
                                   WstkT, WkuT, WvuT, WoT, bq, bkd, bvd, bqkv);

  // QKV projection: 24x32 = 768 blocks (3/CU)
  gemm_bt<128, 64, 1, 0><<<dim3(NQKV / 64, MTOT / 128, 1), 256, 0, stream>>>(
      xb, xb, WstkT, WstkT, bqkv, bqkv, QKVb, QKVb, MTOT, NQKV, DM, DM, QSCALE, DM);
  // K-up (row layout) + V-up (transposed layout): 16x32x2 = 1024 blocks (4/CU)
  gemm_bt<128, 64, 1, 1><<<dim3(DM / 64, MTOT / 128, 2), 256, 0, stream>>>(
      QKVb + 1024, QKVb + 1280, WkuT, WvuT, bku, bvu, Kb, VTb, MTOT, DM, LAT, NQKV, 1.f, 0);

  // 512 blocks x 256 threads: 16 q-blocks x 32 bh, XCD-remapped inside
  attn_fused<<<dim3(SEQ / 128, B_SZ * NH), 256, 0, stream>>>(QKVb, Kb, VTb, CXb);

  // output projection: 16x64 = 1024 blocks (4/CU)
  gemm_bt<64, 64, 0, 0><<<dim3(DM / 64, MTOT / 64, 1), 256, 0, stream>>>(
      CXb, CXb, WoT, WoT, bo, bo, out, out, MTOT, DM, DM, DM, 1.f, 0);
}